// Round 16
// baseline (82.084 us; speedup 1.0000x reference)
//
#include <hip/hip_runtime.h>

#define NV 1448
#define JD 4344    // 3*NV
#define CC 256
#define BB 64
#define QQ 128     // 2*BB
#define NPAD 1456  // 91 tiles of 16
#define NTC 91     // tile-cols
#define NSLICE 13  // row slices of 7 tile-rows (112 rows)
#define PADV 60000.0f

typedef __bf16    bf16x8 __attribute__((ext_vector_type(8)));
typedef _Float16  f16x8  __attribute__((ext_vector_type(8)));
typedef float     f32x4  __attribute__((ext_vector_type(4)));

__device__ __forceinline__ unsigned f2bf(float f) {   // fp32 -> bf16 bits, RNE
    unsigned u = __float_as_uint(f);
    return (u + 0x7FFFu + ((u >> 16) & 1u)) >> 16;
}
union HU { _Float16 h; unsigned short u; };
__device__ __forceinline__ unsigned short f2h(float f) { HU t; t.h = (_Float16)f; return t.u; }
__device__ __forceinline__ float h2f(unsigned short u) { HU t; t.u = u; return (float)t.h; }

// ---------------------------------------------------------------------------
// K1: global average pool -> latQb[q][c] (bf16). Thread 0 zeroes acc.
// ---------------------------------------------------------------------------
__global__ __launch_bounds__(256) void pool_kernel(const float* __restrict__ inp,
                                                   const float* __restrict__ tgt,
                                                   unsigned short* __restrict__ latQb,
                                                   unsigned long long* __restrict__ acc) {
    int gid  = blockIdx.x * 256 + threadIdx.x;
    if (gid == 0) { acc[0] = 0ull; acc[1] = 0ull; }
    int lane = gid & 15;
    int row  = gid >> 4;
    if (row >= 2 * BB * CC) return;
    int t  = row >> 14;
    int bc = row & 16383;
    const float* src = (t ? tgt : inp) + (size_t)bc * 64;
    float4 v = reinterpret_cast<const float4*>(src)[lane];
    float s = (v.x + v.y) + (v.z + v.w);
    s += __shfl_xor(s, 1);
    s += __shfl_xor(s, 2);
    s += __shfl_xor(s, 4);
    s += __shfl_xor(s, 8);
    if (lane == 0) {
        int b = bc >> 8, c = bc & 255;
        latQb[(size_t)(t * 64 + b) * CC + c] = (unsigned short)f2bf(s * (1.0f / 64.0f));
    }
}

// ---------------------------------------------------------------------------
// K2: decode GEMM via bf16 MFMA (R15, proven).
// ---------------------------------------------------------------------------
__global__ __launch_bounds__(256) void decode_kernel(const unsigned short* __restrict__ latQb,
                                                     const float* __restrict__ muL,
                                                     const float* __restrict__ deltaL,
                                                     const float* __restrict__ muR,
                                                     const float* __restrict__ deltaR,
                                                     const int* __restrict__ labels,
                                                     float* __restrict__ pts3) {
    const int jt   = blockIdx.x;
    const int side = blockIdx.y;
    const int qq   = blockIdx.z;
    const float* __restrict__ delta = side ? deltaR : deltaL;
    const float* __restrict__ mu    = side ? muR : muL;
    const int jb = jt * 64;
    const int q0 = qq * 32;
    const int tid  = threadIdx.x;
    const int w    = tid >> 6;
    const int lane = tid & 63;

    __shared__ unsigned short dB[64 * 264];
    __shared__ unsigned short lB[32 * 264];

#pragma unroll
    for (int i = 0; i < 16; ++i) {
        int idx = i * 256 + tid;
        int row = idx >> 6;
        int ch  = idx & 63;
        int j   = jb + row;
        unsigned u0 = 0, u1 = 0;
        if (j < JD) {
            float4 v = *reinterpret_cast<const float4*>(delta + (size_t)j * CC + ch * 4);
            u0 = f2bf(v.x) | (f2bf(v.y) << 16);
            u1 = f2bf(v.z) | (f2bf(v.w) << 16);
        }
        *reinterpret_cast<uint2*>(&dB[row * 264 + ch * 4]) = make_uint2(u0, u1);
    }
#pragma unroll
    for (int i = 0; i < 4; ++i) {
        int idx = i * 256 + tid;
        int row = idx >> 5;
        int ch  = idx & 31;
        *reinterpret_cast<uint4*>(&lB[row * 264 + ch * 8]) =
            *reinterpret_cast<const uint4*>(latQb + (size_t)(q0 + row) * CC + ch * 8);
    }
    __syncthreads();

    const int col  = lane & 15;
    const int kgrp = lane >> 4;
    bf16x8 bfr[8];
#pragma unroll
    for (int ks = 0; ks < 8; ++ks)
        bfr[ks] = *reinterpret_cast<const bf16x8*>(&dB[(w * 16 + col) * 264 + ks * 32 + kgrp * 8]);

    int j = jb + w * 16 + col;
    float muv = (j < JD) ? mu[j] : 0.f;

#pragma unroll
    for (int mt = 0; mt < 2; ++mt) {
        f32x4 acc = {0.f, 0.f, 0.f, 0.f};
#pragma unroll
        for (int ks = 0; ks < 8; ++ks) {
            bf16x8 a = *reinterpret_cast<const bf16x8*>(&lB[(mt * 16 + col) * 264 + ks * 32 + kgrp * 8]);
            acc = __builtin_amdgcn_mfma_f32_16x16x32_bf16(a, bfr[ks], acc, 0, 0, 0);
        }
        if (j < JD) {
#pragma unroll
            for (int r = 0; r < 4; ++r) {
                int q = q0 + mt * 16 + kgrp * 4 + r;
                if (labels[q & 63] == side)
                    pts3[(size_t)q * JD + j] = acc[r] + muv;
            }
        }
    }
}

// ---------------------------------------------------------------------------
// K2b: pack fp16-split MFMA operands. Slots (K index):
//  A (in-side, q<64):  0:ahx 1:ahx 2:alx 3:ahy 4:ahy 5:aly 6:ahz 7:ahz
//                      8:alz 9:1 10:1 11:a2h 12:a2l 13-15:0   (ah=-2x hi, al lo)
//  B (tg-side, q>=64): 0:bhx 1:blx 2:bhx 3:bhy 4:bly 5:bhy 6:bhz 7:blz
//                      8:bhz 9:b2h 10:b2l 11:1 12:1 13-15:0
//  sum_k A[k]*B[k] = -2(a.b) + b^2 + a^2 = d^2, to ~1e-6 (fp32-emulated).
//  Pad points (n>=NV): zero coords, a2h/b2h = 60000 -> never win a min.
// ---------------------------------------------------------------------------
__global__ __launch_bounds__(256) void pack_kernel(const float* __restrict__ pts3,
                                                   unsigned short* __restrict__ Apack,
                                                   unsigned short* __restrict__ Bpack) {
    int idx = blockIdx.x * 256 + threadIdx.x;   // 128*1456 = 186368 = 728*256
    if (idx >= QQ * NPAD) return;
    int q = idx / NPAD;
    int n = idx - q * NPAD;
    float x = 0.f, y = 0.f, z = 0.f;
    bool real = n < NV;
    if (real) {
        const float* p = pts3 + (size_t)q * JD + n * 3;
        x = p[0]; y = p[1]; z = p[2];
    }
    float p2 = fmaf(x, x, fmaf(y, y, z * z));
    if (!real) p2 = PADV;
    unsigned short p2h = f2h(p2);
    unsigned short p2l = f2h(p2 - h2f(p2h));
    unsigned short one = f2h(1.0f);
    unsigned short out[16];
    if (q < BB) {   // A side: -2x split
        unsigned short ahx = f2h(-2.f * x), ahy = f2h(-2.f * y), ahz = f2h(-2.f * z);
        unsigned short alx = f2h(-2.f * x - h2f(ahx));
        unsigned short aly = f2h(-2.f * y - h2f(ahy));
        unsigned short alz = f2h(-2.f * z - h2f(ahz));
        out[0] = ahx; out[1] = ahx; out[2] = alx;
        out[3] = ahy; out[4] = ahy; out[5] = aly;
        out[6] = ahz; out[7] = ahz; out[8] = alz;
        out[9] = one; out[10] = one; out[11] = p2h; out[12] = p2l;
        out[13] = out[14] = out[15] = 0;
        uint4* dst = reinterpret_cast<uint4*>(Apack + ((size_t)q * NPAD + n) * 16);
        dst[0] = *reinterpret_cast<uint4*>(&out[0]);
        dst[1] = *reinterpret_cast<uint4*>(&out[8]);
    } else {        // B side: x split
        unsigned short bhx = f2h(x), bhy = f2h(y), bhz = f2h(z);
        unsigned short blx = f2h(x - h2f(bhx));
        unsigned short bly = f2h(y - h2f(bhy));
        unsigned short blz = f2h(z - h2f(bhz));
        out[0] = bhx; out[1] = blx; out[2] = bhx;
        out[3] = bhy; out[4] = bly; out[5] = bhy;
        out[6] = bhz; out[7] = blz; out[8] = bhz;
        out[9] = p2h; out[10] = p2l; out[11] = one; out[12] = one;
        out[13] = out[14] = out[15] = 0;
        uint4* dst = reinterpret_cast<uint4*>(Bpack + ((size_t)(q - BB) * NPAD + n) * 16);
        dst[0] = *reinterpret_cast<uint4*>(&out[0]);
        dst[1] = *reinterpret_cast<uint4*>(&out[8]);
    }
}

// ---------------------------------------------------------------------------
// K3: chamfer via MFMA — D-tile = d^2 directly; row-mins AND col-mins in one
// pass (pair work halved). grid (slice 0..12, b 0..63) = 832 blocks x 256.
// Block: rows [slice*112, +112) x all 1456 cols. B staged in LDS (46.6KB);
// wave w owns tile-cols [tcs[w], tcs[w+1]); A-frags (7 tile-rows) hoisted.
// Per tile: 1 MFMA + 4 v_min (rm) + 2 v_min3 (cm). kgrp>=2 frags read a
// 16B zero block (products must be 0, not garbage*0=NaN).
// Row-mins complete per block -> sqrt+sum+atomic here; col-mins -> cmin.
// ---------------------------------------------------------------------------
__global__ __launch_bounds__(256) void chamfer_kernel(const unsigned short* __restrict__ Apack,
                                                      const unsigned short* __restrict__ Bpack,
                                                      float* __restrict__ cmin,
                                                      unsigned long long* __restrict__ acc) {
    const int slice = blockIdx.x;
    const int b     = blockIdx.y;
    const int tid   = threadIdx.x;
    const int w     = tid >> 6;
    const int lane  = tid & 63;
    const int col   = lane & 15;
    const int kgrp  = lane >> 4;
    const int half  = kgrp & 1;

    __shared__ unsigned short BsL[NPAD * 16 + 8];   // + 16B zero block @46592
    __shared__ float rmbuf[4 * 112];

    {   // stage Bpack[b]: 2912 uint4, coalesced
        const uint4* src = reinterpret_cast<const uint4*>(Bpack + (size_t)b * NPAD * 16);
        uint4* dst = reinterpret_cast<uint4*>(BsL);
        for (int i = tid; i < 2912; i += 256) dst[i] = src[i];
        if (tid == 0) dst[2912] = make_uint4(0, 0, 0, 0);
    }
    __syncthreads();

    // hoist A-frags: 7 tile-rows (kgrp>=2 duplicates kgrp0/1 — harmless, B side is 0 there)
    const char* Ab = (const char*)(Apack + ((size_t)b * NPAD + slice * 112) * 16);
    f16x8 afr[7];
#pragma unroll
    for (int tr = 0; tr < 7; ++tr)
        afr[tr] = *reinterpret_cast<const f16x8*>(Ab + (tr * 16 + col) * 32 + half * 16);

    float rm[7][4];
#pragma unroll
    for (int tr = 0; tr < 7; ++tr)
#pragma unroll
        for (int r = 0; r < 4; ++r) rm[tr][r] = 1e30f;

    const int tcs[5] = {0, 23, 46, 69, 91};
    const char* Bb = (const char*)BsL;
    const f32x4 zero4 = {0.f, 0.f, 0.f, 0.f};

    for (int tc = tcs[w]; tc < tcs[w + 1]; ++tc) {
        int daddr = (tc * 16 + col) * 32 + half * 16;
        int addr  = (kgrp < 2) ? daddr : (NPAD * 32);
        f16x8 bfrag = *reinterpret_cast<const f16x8*>(Bb + addr);
        float cmv = 1e30f;
#pragma unroll
        for (int tr = 0; tr < 7; ++tr) {
            f32x4 d = __builtin_amdgcn_mfma_f32_16x16x32_f16(afr[tr], bfrag, zero4, 0, 0, 0);
            rm[tr][0] = fminf(rm[tr][0], d[0]);
            rm[tr][1] = fminf(rm[tr][1], d[1]);
            rm[tr][2] = fminf(rm[tr][2], d[2]);
            rm[tr][3] = fminf(rm[tr][3], d[3]);
            float t;
            asm("v_min3_f32 %0, %1, %2, %3" : "=v"(t) : "v"(d[0]), "v"(d[1]), "v"(d[2]));
            asm("v_min3_f32 %0, %0, %1, %2" : "+v"(cmv) : "v"(t), "v"(d[3]));
        }
        // col-min: merge the 4 kgrp row-groups
        cmv = fminf(cmv, __shfl_xor(cmv, 16));
        cmv = fminf(cmv, __shfl_xor(cmv, 32));
        if (lane < 16)
            cmin[((size_t)slice * BB + b) * NPAD + tc * 16 + lane] = cmv;
    }

    // row-min: reduce across the 16 col-lanes, then cross-wave via LDS
#pragma unroll
    for (int tr = 0; tr < 7; ++tr)
#pragma unroll
        for (int r = 0; r < 4; ++r) {
            float v = rm[tr][r];
            v = fminf(v, __shfl_xor(v, 1));
            v = fminf(v, __shfl_xor(v, 2));
            v = fminf(v, __shfl_xor(v, 4));
            v = fminf(v, __shfl_xor(v, 8));
            if (col == 0) rmbuf[w * 112 + tr * 16 + kgrp * 4 + r] = v;
        }
    __syncthreads();

    float s = 0.f;
    if (tid < 112) {
        int row = slice * 112 + tid;
        if (row < NV) {
            float v = fminf(fminf(rmbuf[tid], rmbuf[112 + tid]),
                            fminf(rmbuf[224 + tid], rmbuf[336 + tid]));
            s = sqrtf(fmaxf(v, 1e-12f));
        }
    }
    s += __shfl_xor(s, 1);
    s += __shfl_xor(s, 2);
    s += __shfl_xor(s, 4);
    s += __shfl_xor(s, 8);
    s += __shfl_xor(s, 16);
    s += __shfl_xor(s, 32);
    __shared__ float wsum[4];
    if ((tid & 63) == 0) wsum[tid >> 6] = s;
    __syncthreads();
    if (tid == 0) {
        float bs = (wsum[0] + wsum[1]) + (wsum[2] + wsum[3]);
        atomicAdd(acc, (unsigned long long)((double)bs * 16777216.0));
    }
}

// ---------------------------------------------------------------------------
// K4: combine col-mins (13 slices), sqrt, sum -> atomic; last block writes.
// 364 blocks x 256 = 93184 = 64*1456 exact.
// ---------------------------------------------------------------------------
__global__ __launch_bounds__(256) void combine_kernel(const float* __restrict__ cmin,
                                                      unsigned long long* __restrict__ acc,
                                                      float* __restrict__ out) {
    int idx = blockIdx.x * 256 + threadIdx.x;
    int b = idx / NPAD;
    int n = idx - b * NPAD;
    float s = 0.f;
    if (n < NV) {
        float v = 1e30f;
#pragma unroll
        for (int sl = 0; sl < NSLICE; ++sl)
            v = fminf(v, cmin[((size_t)sl * BB + b) * NPAD + n]);
        s = sqrtf(fmaxf(v, 1e-12f));
    }
    s += __shfl_xor(s, 1);
    s += __shfl_xor(s, 2);
    s += __shfl_xor(s, 4);
    s += __shfl_xor(s, 8);
    s += __shfl_xor(s, 16);
    s += __shfl_xor(s, 32);
    __shared__ float wsum[4];
    if ((threadIdx.x & 63) == 0) wsum[threadIdx.x >> 6] = s;
    __syncthreads();
    if (threadIdx.x == 0) {
        float bs = (wsum[0] + wsum[1]) + (wsum[2] + wsum[3]);
        atomicAdd(acc, (unsigned long long)((double)bs * 16777216.0));
        __threadfence();
        unsigned long long done = atomicAdd(acc + 1, 1ull);
        if (done == 363) {
            __threadfence();
            unsigned long long total = atomicAdd(acc, 0ull);
            out[0] = (float)((double)total * (0x1p-24 / (64.0 * 1448.0)));
        }
    }
}

extern "C" void kernel_launch(void* const* d_in, const int* in_sizes, int n_in,
                              void* d_out, int out_size, void* d_ws, size_t ws_size,
                              hipStream_t stream) {
    const float* inp    = (const float*)d_in[0];
    const float* tgt    = (const float*)d_in[1];
    const int*   labels = (const int*)d_in[2];
    const float* muL    = (const float*)d_in[3];
    const float* deltaL = (const float*)d_in[4];
    const float* muR    = (const float*)d_in[5];
    const float* deltaR = (const float*)d_in[6];
    float* out = (float*)d_out;

    char* ws = (char*)d_ws;
    unsigned short* latQb = (unsigned short*)ws;                      // 65536 B
    float* pts3           = (float*)(ws + 65536);                     // 2224128 B
    unsigned short* Apack = (unsigned short*)(ws + 65536 + 2224128);  // 64*1456*32 = 2981888 B
    unsigned short* Bpack = (unsigned short*)(ws + 5271552);          // 2981888 B
    float* cmin           = (float*)(ws + 8253440);                   // 13*64*1456*4 = 4845568 B
    unsigned long long* acc = (unsigned long long*)(ws + 13099008);

    hipLaunchKernelGGL(pool_kernel, dim3(2048), dim3(256), 0, stream, inp, tgt, latQb, acc);
    hipLaunchKernelGGL(decode_kernel, dim3(68, 2, 4), dim3(256), 0, stream,
                       latQb, muL, deltaL, muR, deltaR, labels, pts3);
    hipLaunchKernelGGL(pack_kernel, dim3(728), dim3(256), 0, stream, pts3, Apack, Bpack);
    hipLaunchKernelGGL(chamfer_kernel, dim3(NSLICE, BB), dim3(256), 0, stream,
                       Apack, Bpack, cmin, acc);
    hipLaunchKernelGGL(combine_kernel, dim3(364), dim3(256), 0, stream, cmin, acc, out);
}

// Round 17
// 60.521 us; speedup vs baseline: 1.3563x; 1.3563x over previous
//
#include <hip/hip_runtime.h>

#define NV 1448
#define JD 4344     // 3*NV
#define CC 256
#define BB 64
#define QQ 128      // 2*BB
#define NPAD32 1472 // 46 tiles of 32
#define NTR 46
#define NRSL 8      // row slices (6 tile-rows each, last 4)
#define PADV 60000.0f

typedef __bf16    bf16x8 __attribute__((ext_vector_type(8)));
typedef _Float16  f16x8  __attribute__((ext_vector_type(8)));
typedef float     f32x4  __attribute__((ext_vector_type(4)));
typedef float     f32x16 __attribute__((ext_vector_type(16)));

__device__ __forceinline__ unsigned f2bf(float f) {
    unsigned u = __float_as_uint(f);
    return (u + 0x7FFFu + ((u >> 16) & 1u)) >> 16;
}
union HU { _Float16 h; unsigned short u; };
__device__ __forceinline__ unsigned short f2h(float f) { HU t; t.h = (_Float16)f; return t.u; }
__device__ __forceinline__ float h2f(unsigned short u) { HU t; t.u = u; return (float)t.h; }

#define MIN3(dst, a, b, c) asm("v_min3_f32 %0, %1, %2, %3" : "=v"(dst) : "v"(a), "v"(b), "v"(c))
#define MIN3A(dst, a, b)   asm("v_min3_f32 %0, %0, %1, %2" : "+v"(dst) : "v"(a), "v"(b))

// ---------------------------------------------------------------------------
// K1: global average pool -> latQb[q][c] (bf16). Thread 0 zeroes acc.
// ---------------------------------------------------------------------------
__global__ __launch_bounds__(256) void pool_kernel(const float* __restrict__ inp,
                                                   const float* __restrict__ tgt,
                                                   unsigned short* __restrict__ latQb,
                                                   unsigned long long* __restrict__ acc) {
    int gid  = blockIdx.x * 256 + threadIdx.x;
    if (gid == 0) { acc[0] = 0ull; acc[1] = 0ull; }
    int lane = gid & 15;
    int row  = gid >> 4;
    if (row >= 2 * BB * CC) return;
    int t  = row >> 14;
    int bc = row & 16383;
    const float* src = (t ? tgt : inp) + (size_t)bc * 64;
    float4 v = reinterpret_cast<const float4*>(src)[lane];
    float s = (v.x + v.y) + (v.z + v.w);
    s += __shfl_xor(s, 1);
    s += __shfl_xor(s, 2);
    s += __shfl_xor(s, 4);
    s += __shfl_xor(s, 8);
    if (lane == 0) {
        int b = bc >> 8, c = bc & 255;
        latQb[(size_t)(t * 64 + b) * CC + c] = (unsigned short)f2bf(s * (1.0f / 64.0f));
    }
}

// ---------------------------------------------------------------------------
// K2: decode GEMM via bf16 MFMA (R15, proven).
// ---------------------------------------------------------------------------
__global__ __launch_bounds__(256) void decode_kernel(const unsigned short* __restrict__ latQb,
                                                     const float* __restrict__ muL,
                                                     const float* __restrict__ deltaL,
                                                     const float* __restrict__ muR,
                                                     const float* __restrict__ deltaR,
                                                     const int* __restrict__ labels,
                                                     float* __restrict__ pts3) {
    const int jt   = blockIdx.x;
    const int side = blockIdx.y;
    const int qq   = blockIdx.z;
    const float* __restrict__ delta = side ? deltaR : deltaL;
    const float* __restrict__ mu    = side ? muR : muL;
    const int jb = jt * 64;
    const int q0 = qq * 32;
    const int tid  = threadIdx.x;
    const int w    = tid >> 6;
    const int lane = tid & 63;

    __shared__ unsigned short dB[64 * 264];
    __shared__ unsigned short lB[32 * 264];

#pragma unroll
    for (int i = 0; i < 16; ++i) {
        int idx = i * 256 + tid;
        int row = idx >> 6;
        int ch  = idx & 63;
        int j   = jb + row;
        unsigned u0 = 0, u1 = 0;
        if (j < JD) {
            float4 v = *reinterpret_cast<const float4*>(delta + (size_t)j * CC + ch * 4);
            u0 = f2bf(v.x) | (f2bf(v.y) << 16);
            u1 = f2bf(v.z) | (f2bf(v.w) << 16);
        }
        *reinterpret_cast<uint2*>(&dB[row * 264 + ch * 4]) = make_uint2(u0, u1);
    }
#pragma unroll
    for (int i = 0; i < 4; ++i) {
        int idx = i * 256 + tid;
        int row = idx >> 5;
        int ch  = idx & 31;
        *reinterpret_cast<uint4*>(&lB[row * 264 + ch * 8]) =
            *reinterpret_cast<const uint4*>(latQb + (size_t)(q0 + row) * CC + ch * 8);
    }
    __syncthreads();

    const int col  = lane & 15;
    const int kgrp = lane >> 4;
    bf16x8 bfr[8];
#pragma unroll
    for (int ks = 0; ks < 8; ++ks)
        bfr[ks] = *reinterpret_cast<const bf16x8*>(&dB[(w * 16 + col) * 264 + ks * 32 + kgrp * 8]);

    int j = jb + w * 16 + col;
    float muv = (j < JD) ? mu[j] : 0.f;

#pragma unroll
    for (int mt = 0; mt < 2; ++mt) {
        f32x4 acc = {0.f, 0.f, 0.f, 0.f};
#pragma unroll
        for (int ks = 0; ks < 8; ++ks) {
            bf16x8 a = *reinterpret_cast<const bf16x8*>(&lB[(mt * 16 + col) * 264 + ks * 32 + kgrp * 8]);
            acc = __builtin_amdgcn_mfma_f32_16x16x32_bf16(a, bfr[ks], acc, 0, 0, 0);
        }
        if (j < JD) {
#pragma unroll
            for (int r = 0; r < 4; ++r) {
                int q = q0 + mt * 16 + kgrp * 4 + r;
                if (labels[q & 63] == side)
                    pts3[(size_t)q * JD + j] = acc[r] + muv;
            }
        }
    }
}

// ---------------------------------------------------------------------------
// K2b: pack fp16-split MFMA operands (13 of K=16 slots; R16 math, proven):
//  A (in, q<64):  0:ahx 1:ahx 2:alx 3:ahy 4:ahy 5:aly 6:ahz 7:ahz 8:alz
//                 9:1 10:1 11:a2h 12:a2l 13-15:0   (ah = -2x hi, al = lo)
//  B (tg, q>=64): 0:bhx 1:blx 2:bhx 3:bhy 4:bly 5:bhy 6:bhz 7:blz 8:bhz
//                 9:b2h 10:b2l 11:1 12:1 13-15:0
//  dot = -2 a.b + |b|^2 + |a|^2 = d^2 (fp32-emulated). Pads carry 60000.
// ---------------------------------------------------------------------------
__global__ __launch_bounds__(256) void pack_kernel(const float* __restrict__ pts3,
                                                   unsigned short* __restrict__ Apack,
                                                   unsigned short* __restrict__ Bpack) {
    int idx = blockIdx.x * 256 + threadIdx.x;   // 128*1472 = 188416 = 736*256
    if (idx >= QQ * NPAD32) return;
    int q = idx / NPAD32;
    int n = idx - q * NPAD32;
    float x = 0.f, y = 0.f, z = 0.f;
    bool real = n < NV;
    if (real) {
        const float* p = pts3 + (size_t)q * JD + n * 3;
        x = p[0]; y = p[1]; z = p[2];
    }
    float p2 = fmaf(x, x, fmaf(y, y, z * z));
    if (!real) p2 = PADV;
    unsigned short p2h = f2h(p2);
    unsigned short p2l = f2h(p2 - h2f(p2h));
    unsigned short one = f2h(1.0f);
    unsigned short out[16];
    if (q < BB) {
        unsigned short ahx = f2h(-2.f * x), ahy = f2h(-2.f * y), ahz = f2h(-2.f * z);
        unsigned short alx = f2h(-2.f * x - h2f(ahx));
        unsigned short aly = f2h(-2.f * y - h2f(ahy));
        unsigned short alz = f2h(-2.f * z - h2f(ahz));
        out[0] = ahx; out[1] = ahx; out[2] = alx;
        out[3] = ahy; out[4] = ahy; out[5] = aly;
        out[6] = ahz; out[7] = ahz; out[8] = alz;
        out[9] = one; out[10] = one; out[11] = p2h; out[12] = p2l;
        out[13] = out[14] = out[15] = 0;
        uint4* dst = reinterpret_cast<uint4*>(Apack + ((size_t)q * NPAD32 + n) * 16);
        dst[0] = *reinterpret_cast<uint4*>(&out[0]);
        dst[1] = *reinterpret_cast<uint4*>(&out[8]);
    } else {
        unsigned short bhx = f2h(x), bhy = f2h(y), bhz = f2h(z);
        unsigned short blx = f2h(x - h2f(bhx));
        unsigned short bly = f2h(y - h2f(bhy));
        unsigned short blz = f2h(z - h2f(bhz));
        out[0] = bhx; out[1] = blx; out[2] = bhx;
        out[3] = bhy; out[4] = bly; out[5] = bhy;
        out[6] = bhz; out[7] = blz; out[8] = bhz;
        out[9] = p2h; out[10] = p2l; out[11] = one; out[12] = one;
        out[13] = out[14] = out[15] = 0;
        uint4* dst = reinterpret_cast<uint4*>(Bpack + ((size_t)(q - BB) * NPAD32 + n) * 16);
        dst[0] = *reinterpret_cast<uint4*>(&out[0]);
        dst[1] = *reinterpret_cast<uint4*>(&out[8]);
    }
}

// ---------------------------------------------------------------------------
// K3: chamfer via 32x32x16 f16 MFMA. D tile = 1024 d^2; row-min AND col-min
// per tile (16 min3 per 2 tiles for rm, 8-op min3 tree for cm).
// grid (b 0..63, rslice 0..7) = 512 blocks x 256 thr (2 blk/CU, 8 waves/CU).
// Block: 6 tile-rows (last slice 4) x 46 tile-cols; waves split tile-cols.
// B (47KB) XOR-swizzled in LDS (u4 idx ^= (u4>>3)&7: 8-way -> 4-way reads).
// A frags from global (L1-cached). rmw merge buffer stride 17 (conflict-free).
// C/D: col=lane&31, row=(reg&3)+8*(reg>>2)+4*(lane>>5) [m74/m101].
// ---------------------------------------------------------------------------
__global__ __launch_bounds__(256) void chamfer_kernel(const unsigned short* __restrict__ Apack,
                                                      const unsigned short* __restrict__ Bpack,
                                                      float* __restrict__ cmin,
                                                      unsigned long long* __restrict__ acc) {
    const int b      = blockIdx.x;
    const int rslice = blockIdx.y;
    const int tr0    = rslice * 6;
    const int ntr    = (rslice == 7) ? 4 : 6;   // 46 = 7*6 + 4
    const int tid  = threadIdx.x;
    const int w    = tid >> 6;
    const int lane = tid & 63;
    const int col  = lane & 31;
    const int half = lane >> 5;

    __shared__ unsigned short BsL[NPAD32 * 16];     // 47104 B, swizzled
    __shared__ float rmw[4][64][17];                // 17408 B, stride-17
    __shared__ float wsum[4];

    {   // stage B with XOR swizzle (write & read use the same bijection)
        const uint4* src = reinterpret_cast<const uint4*>(Bpack + (size_t)b * NPAD32 * 16);
        uint4* dst = reinterpret_cast<uint4*>(BsL);
        for (int i = tid; i < NPAD32 * 2; i += 256)
            dst[i ^ ((i >> 3) & 7)] = src[i];
    }
    __syncthreads();

    const int tcs[5] = {0, 12, 24, 35, 46};
    const int my0 = tcs[w], my1 = tcs[w + 1];
    const int nslots = my1 - my0;

    float cmAcc[12];
#pragma unroll
    for (int i = 0; i < 12; ++i) cmAcc[i] = 1e30f;

    f32x16 zero16;
#pragma unroll
    for (int i = 0; i < 16; ++i) zero16[i] = 0.f;

    float ssum = 0.f;
    const char* Bb = (const char*)BsL;

#define BFRAG(tc) (*reinterpret_cast<const f16x8*>(Bb + 16 * ((((tc) * 64 + col * 2 + half)) ^ (((((tc) * 64 + col * 2 + half)) >> 3) & 7))))
#define CTREE(dd, slot) do { float t0, t1, t2v, t3, t4, u0, u1; \
    MIN3(t0, dd[0], dd[1], dd[2]);   MIN3(t1, dd[3], dd[4], dd[5]); \
    MIN3(t2v, dd[6], dd[7], dd[8]);  MIN3(t3, dd[9], dd[10], dd[11]); \
    MIN3(t4, dd[12], dd[13], dd[14]); \
    MIN3(u0, t0, t1, t2v); MIN3(u1, t3, t4, dd[15]); \
    MIN3A(cmAcc[slot], u0, u1); } while (0)

    for (int trl = 0; trl < ntr; ++trl) {
        const int tr = tr0 + trl;
        f16x8 afr = *reinterpret_cast<const f16x8*>(
            Apack + ((size_t)b * NPAD32 + tr * 32 + col) * 16 + half * 8);

        float rm[16];
#pragma unroll
        for (int i = 0; i < 16; ++i) rm[i] = 1e30f;

        int t2 = my0;
        for (; t2 + 1 < my1; t2 += 2) {
            f16x8 bf0 = BFRAG(t2);
            f16x8 bf1 = BFRAG(t2 + 1);
            f32x16 d0 = __builtin_amdgcn_mfma_f32_32x32x16_f16(afr, bf0, zero16, 0, 0, 0);
            f32x16 d1 = __builtin_amdgcn_mfma_f32_32x32x16_f16(afr, bf1, zero16, 0, 0, 0);
#pragma unroll
            for (int i = 0; i < 16; ++i)
                MIN3A(rm[i], d0[i], d1[i]);
            CTREE(d0, t2 - my0);
            CTREE(d1, t2 + 1 - my0);
        }
        if (t2 < my1) {   // odd tail
            f16x8 bf0 = BFRAG(t2);
            f32x16 d0 = __builtin_amdgcn_mfma_f32_32x32x16_f16(afr, bf0, zero16, 0, 0, 0);
#pragma unroll
            for (int i = 0; i < 16; ++i) rm[i] = fminf(rm[i], d0[i]);
            CTREE(d0, t2 - my0);
        }

        // cross-wave/cross-col row-min merge for these 32 rows
#pragma unroll
        for (int i = 0; i < 16; ++i) rmw[w][lane][i] = rm[i];
        __syncthreads();
        {
            int R = tid >> 3, k = tid & 7;            // 32 rows x 8 helpers
            int reg = (R & 3) | ((R >> 3) << 2);
            int h   = (R >> 2) & 1;
            float v = 1e30f;
#pragma unroll
            for (int ww = 0; ww < 4; ++ww) {
                v = fminf(v, rmw[ww][h * 32 + k][reg]);
                v = fminf(v, rmw[ww][h * 32 + k + 8][reg]);
                v = fminf(v, rmw[ww][h * 32 + k + 16][reg]);
                v = fminf(v, rmw[ww][h * 32 + k + 24][reg]);
            }
            v = fminf(v, __shfl_xor(v, 1));
            v = fminf(v, __shfl_xor(v, 2));
            v = fminf(v, __shfl_xor(v, 4));
            if (k == 0) {
                int row = tr * 32 + R;
                if (row < NV) ssum += sqrtf(fmaxf(v, 1e-12f));
            }
        }
        __syncthreads();
    }

    // col-min write (partial over this rslice's rows; combine merges slices)
#pragma unroll
    for (int s = 0; s < 12; ++s) {
        if (s < nslots) {
            float cmv = fminf(cmAcc[s], __shfl_xor(cmAcc[s], 32));
            if (half == 0) {
                int tc = my0 + s;
                cmin[((size_t)rslice * BB + b) * NPAD32 + tc * 32 + col] = cmv;
            }
        }
    }

    // block sum of row sqrts -> fixed-point atomic
    ssum += __shfl_xor(ssum, 1);
    ssum += __shfl_xor(ssum, 2);
    ssum += __shfl_xor(ssum, 4);
    ssum += __shfl_xor(ssum, 8);
    ssum += __shfl_xor(ssum, 16);
    ssum += __shfl_xor(ssum, 32);
    if ((tid & 63) == 0) wsum[w] = ssum;
    __syncthreads();
    if (tid == 0) {
        float bs = (wsum[0] + wsum[1]) + (wsum[2] + wsum[3]);
        atomicAdd(acc, (unsigned long long)((double)bs * 16777216.0));
    }
}

// ---------------------------------------------------------------------------
// K4: combine col-mins (8 slices), sqrt, sum -> atomic; last block writes.
// 368 blocks x 256 = 94208 = 64*1472 exact.
// ---------------------------------------------------------------------------
__global__ __launch_bounds__(256) void combine_kernel(const float* __restrict__ cmin,
                                                      unsigned long long* __restrict__ acc,
                                                      float* __restrict__ out) {
    int idx = blockIdx.x * 256 + threadIdx.x;
    int b = idx / NPAD32;
    int n = idx - b * NPAD32;
    float s = 0.f;
    if (n < NV) {
        float v = 1e30f;
#pragma unroll
        for (int sl = 0; sl < NRSL; ++sl)
            v = fminf(v, cmin[((size_t)sl * BB + b) * NPAD32 + n]);
        s = sqrtf(fmaxf(v, 1e-12f));
    }
    s += __shfl_xor(s, 1);
    s += __shfl_xor(s, 2);
    s += __shfl_xor(s, 4);
    s += __shfl_xor(s, 8);
    s += __shfl_xor(s, 16);
    s += __shfl_xor(s, 32);
    __shared__ float wsum[4];
    if ((threadIdx.x & 63) == 0) wsum[threadIdx.x >> 6] = s;
    __syncthreads();
    if (threadIdx.x == 0) {
        float bs = (wsum[0] + wsum[1]) + (wsum[2] + wsum[3]);
        atomicAdd(acc, (unsigned long long)((double)bs * 16777216.0));
        __threadfence();
        unsigned long long done = atomicAdd(acc + 1, 1ull);
        if (done == 367) {
            __threadfence();
            unsigned long long total = atomicAdd(acc, 0ull);
            out[0] = (float)((double)total * (0x1p-24 / (64.0 * 1448.0)));
        }
    }
}

extern "C" void kernel_launch(void* const* d_in, const int* in_sizes, int n_in,
                              void* d_out, int out_size, void* d_ws, size_t ws_size,
                              hipStream_t stream) {
    const float* inp    = (const float*)d_in[0];
    const float* tgt    = (const float*)d_in[1];
    const int*   labels = (const int*)d_in[2];
    const float* muL    = (const float*)d_in[3];
    const float* deltaL = (const float*)d_in[4];
    const float* muR    = (const float*)d_in[5];
    const float* deltaR = (const float*)d_in[6];
    float* out = (float*)d_out;

    char* ws = (char*)d_ws;
    unsigned short* latQb = (unsigned short*)ws;                      // 65536 B
    float* pts3           = (float*)(ws + 65536);                     // 2224128 B
    unsigned short* Apack = (unsigned short*)(ws + 2289664);          // 64*1472*32 = 3014656 B
    unsigned short* Bpack = (unsigned short*)(ws + 5304320);          // 3014656 B
    float* cmin           = (float*)(ws + 8318976);                   // 8*64*1472*4 = 3014656 B
    unsigned long long* acc = (unsigned long long*)(ws + 11333632);

    hipLaunchKernelGGL(pool_kernel, dim3(2048), dim3(256), 0, stream, inp, tgt, latQb, acc);
    hipLaunchKernelGGL(decode_kernel, dim3(68, 2, 4), dim3(256), 0, stream,
                       latQb, muL, deltaL, muR, deltaR, labels, pts3);
    hipLaunchKernelGGL(pack_kernel, dim3(736), dim3(256), 0, stream, pts3, Apack, Bpack);
    hipLaunchKernelGGL(chamfer_kernel, dim3(BB, NRSL), dim3(256), 0, stream,
                       Apack, Bpack, cmin, acc);
    hipLaunchKernelGGL(combine_kernel, dim3(368), dim3(256), 0, stream, cmin, acc, out);
}